// Round 6
// baseline (227.499 us; speedup 1.0000x reference)
//
#include <hip/hip_runtime.h>

#define B_  2
#define T_  2048
#define C_  1024
#define H_  16
#define HS_ 64
#define M_  4096   // B_*T_
#define N3_ 3072

typedef __bf16 bf16;
typedef bf16  bf16x4 __attribute__((ext_vector_type(4)));
typedef bf16  bf16x8 __attribute__((ext_vector_type(8)));
typedef float f32x4  __attribute__((ext_vector_type(4)));

__device__ __forceinline__ bf16 f2bf(float x) {
  union { float f; unsigned u; } v; v.f = x;
  unsigned r = (v.u + 0x7FFFu + ((v.u >> 16) & 1u)) >> 16;
  union { unsigned short s; bf16 b; } o; o.s = (unsigned short)r;
  return o.b;
}

// pack two fp32 -> two bf16 (round-to-nearest-ish via +0x8000), lane-local, ~3 VALU ops
__device__ __forceinline__ unsigned pk2bf(float lo, float hi) {
  union { float f; unsigned u; } a, b;
  a.f = lo; b.f = hi;
  return ((a.u + 0x8000u) >> 16) | ((b.u + 0x8000u) & 0xFFFF0000u);
}

#define GLB(p) ((const __attribute__((address_space(1))) void*)(p))
#define LDSP(p) ((__attribute__((address_space(3))) void*)(p))

// ---------------- cast x -> bf16 ----------------
__global__ __launch_bounds__(256) void cast_x_kernel(const float* __restrict__ in,
                                                     bf16* __restrict__ out, int n4) {
  int i = blockIdx.x * 256 + threadIdx.x;
  if (i >= n4) return;
  float4 v = ((const float4*)in)[i];
  bf16 o[4] = {f2bf(v.x), f2bf(v.y), f2bf(v.z), f2bf(v.w)};
  *(uint2*)(out + (size_t)i * 4) = *(uint2*)o;
}

// ---------------- transpose + cast: in fp32 [R][Cc] -> out bf16 [Cc][R] ----------------
__global__ __launch_bounds__(256) void transpose_cast(const float* __restrict__ in,
                                                      bf16* __restrict__ out, int R, int Cc) {
  __shared__ float tile[32][33];
  int c0 = blockIdx.x * 32, r0 = blockIdx.y * 32;
  int tx = threadIdx.x, ty = threadIdx.y;
  #pragma unroll
  for (int i = ty; i < 32; i += 8)
    tile[i][tx] = in[(size_t)(r0 + i) * Cc + c0 + tx];
  __syncthreads();
  #pragma unroll
  for (int i = ty; i < 32; i += 8)
    out[(size_t)(c0 + i) * R + r0 + tx] = f2bf(tile[tx][i]);
}

// ---------------- transpose+cast W_l1/W_l2 (64x64 fp32) -> bf16 [j][d] ----------------
__global__ __launch_bounds__(256) void cast_wl_kernel(const float* __restrict__ W1,
                                                      const float* __restrict__ W2,
                                                      bf16* __restrict__ W1T,
                                                      bf16* __restrict__ W2T) {
  const int tid = blockIdx.x * 256 + threadIdx.x;   // 8192 total
  const int m = tid >> 12, e = tid & 4095;
  const int j = e >> 6, d = e & 63;
  const float* src = m ? W2 : W1;
  bf16* dst = m ? W2T : W1T;
  dst[e] = f2bf(src[d * 64 + j]);
}

// ---------------- 128x128 tile bf16 MFMA GEMM: C = A[M,K] * Bt[N,K]^T + bias ----------------
// MODE 0: split epilogue -> Qo (x 0.125*log2e, exp2-domain flash), Ko, Vo (all bf16)
// MODE 1: fp32 out Fo [M][N]
template<int MODE>
__global__ __launch_bounds__(256)
void gemm128(const bf16* __restrict__ A, const bf16* __restrict__ Bt,
             const float* __restrict__ bias,
             bf16* __restrict__ Qo, bf16* __restrict__ Ko, bf16* __restrict__ Vo,
             float* __restrict__ Fo, int K) {
  __shared__ bf16 As[128 * 32];
  __shared__ bf16 Bs[128 * 32];
  const int tid = threadIdx.x;
  const int lane = tid & 63, w = tid >> 6;
  const int l = lane & 15, quad = lane >> 4;
  const int m0 = blockIdx.y * 128, n0 = blockIdx.x * 128;
  const int wm = (w >> 1) * 64, wn = (w & 1) * 64;

  f32x4 acc[4][4];
  #pragma unroll
  for (int i = 0; i < 4; ++i)
    #pragma unroll
    for (int j = 0; j < 4; ++j)
      acc[i][j] = (f32x4){0.f, 0.f, 0.f, 0.f};

  const int soff0 = tid * 16;  // byte offset, chunk 0 of 8KB tile

  for (int k0 = 0; k0 < K; k0 += 32) {
    #pragma unroll
    for (int ch = 0; ch < 2; ++ch) {
      const int off = soff0 + ch * 4096;
      const int row = off >> 6;          // tile row (64B = 32 bf16 per row)
      const int ce  = (off & 63) >> 1;   // element col within 32
      const bf16* ga = A  + (size_t)(m0 + row) * K + (k0 + ce);
      const bf16* gb = Bt + (size_t)(n0 + row) * K + (k0 + ce);
      __builtin_amdgcn_global_load_lds(GLB(ga), LDSP((char*)As + off), 16, 0, 0);
      __builtin_amdgcn_global_load_lds(GLB(gb), LDSP((char*)Bs + off), 16, 0, 0);
    }
    __syncthreads();  // drains vmcnt before barrier (m97 structure)

    bf16x8 af[4], bfr[4];
    #pragma unroll
    for (int rb = 0; rb < 4; ++rb)
      af[rb] = *(const bf16x8*)(As + (wm + rb * 16 + l) * 32 + quad * 8);
    #pragma unroll
    for (int cb = 0; cb < 4; ++cb)
      bfr[cb] = *(const bf16x8*)(Bs + (wn + cb * 16 + l) * 32 + quad * 8);
    #pragma unroll
    for (int rb = 0; rb < 4; ++rb)
      #pragma unroll
      for (int cb = 0; cb < 4; ++cb)
        acc[rb][cb] = __builtin_amdgcn_mfma_f32_16x16x32_bf16(af[rb], bfr[cb], acc[rb][cb], 0, 0, 0);
    __syncthreads();
  }

  #pragma unroll
  for (int rb = 0; rb < 4; ++rb) {
    #pragma unroll
    for (int cb = 0; cb < 4; ++cb) {
      #pragma unroll
      for (int r = 0; r < 4; ++r) {
        const int row = m0 + wm + rb * 16 + quad * 4 + r;
        const int col = n0 + wn + cb * 16 + l;
        float v = acc[rb][cb][r] + bias[col];
        if constexpr (MODE == 0) {
          const int seg = col >> 10, cc = col & 1023;
          const size_t idx = (size_t)row * C_ + cc;
          // Q scale = (1/sqrt(64)) * log2(e): flash softmax runs in exp2 domain
          if (seg == 0)      Qo[idx] = f2bf(v * 0.1803368801f);
          else if (seg == 1) Ko[idx] = f2bf(v);
          else               Vo[idx] = f2bf(v);
        } else {
          Fo[(size_t)row * C_ + col] = v;
        }
      }
    }
  }
}

// ---------------- v-gating via MFMA: gv = (v + v@W1 + b1) * sigmoid(v@W2 + b2) ----------------
__global__ __launch_bounds__(256)
void gate_kernel(const bf16* __restrict__ V, const bf16* __restrict__ W1T,
                 const float* __restrict__ b1, const bf16* __restrict__ W2T,
                 const float* __restrict__ b2, bf16* __restrict__ GVt) {
  __shared__ bf16 Vs[128 * 64];
  __shared__ bf16 W1s[64 * 64];
  __shared__ bf16 W2s[64 * 64];
  const int tid = threadIdx.x, w = tid >> 6, lane = tid & 63;
  const int l = lane & 15, quad = lane >> 4;
  const int bh = blockIdx.y;
  const int t0 = blockIdx.x * 128;
  const int b = bh >> 4, h = bh & 15;
  const int bT = b * T_, hc = h * 64, bh64 = bh * 64;

  #pragma unroll
  for (int i = 0; i < 4; ++i) {
    const int p = tid + i * 256;
    const int row = p >> 3, cc = (p & 7) ^ (row & 7);
    const bf16* gv = V + (size_t)(bT + t0 + row) * C_ + hc + cc * 8;
    __builtin_amdgcn_global_load_lds(GLB(gv), LDSP((char*)Vs + p * 16), 16, 0, 0);
  }
  #pragma unroll
  for (int i = 0; i < 2; ++i) {
    const int p = tid + i * 256;
    const int row = p >> 3, cc = (p & 7) ^ (row & 7);
    __builtin_amdgcn_global_load_lds(GLB(W1T + row * 64 + cc * 8), LDSP((char*)W1s + p * 16), 16, 0, 0);
    __builtin_amdgcn_global_load_lds(GLB(W2T + row * 64 + cc * 8), LDSP((char*)W2s + p * 16), 16, 0, 0);
  }
  __syncthreads();

  const int tb = w * 32;
  bf16x8 af[2][2];
  #pragma unroll
  for (int mt = 0; mt < 2; ++mt) {
    const int row = tb + mt * 16 + l;
    #pragma unroll
    for (int kc = 0; kc < 2; ++kc)
      af[mt][kc] = *(const bf16x8*)(Vs + row * 64 + (((kc * 4 + quad) ^ (row & 7)) * 8));
  }
  bf16x8 w1f[4][2], w2f[4][2];
  #pragma unroll
  for (int nt = 0; nt < 4; ++nt) {
    const int row = nt * 16 + l;
    #pragma unroll
    for (int kc = 0; kc < 2; ++kc) {
      const int off = row * 64 + (((kc * 4 + quad) ^ (row & 7)) * 8);
      w1f[nt][kc] = *(const bf16x8*)(W1s + off);
      w2f[nt][kc] = *(const bf16x8*)(W2s + off);
    }
  }

  #pragma unroll
  for (int mt = 0; mt < 2; ++mt) {
    #pragma unroll
    for (int nt = 0; nt < 4; ++nt) {
      f32x4 a1 = __builtin_amdgcn_mfma_f32_16x16x32_bf16(af[mt][0], w1f[nt][0],
                                                         (f32x4){0.f,0.f,0.f,0.f}, 0, 0, 0);
      a1 = __builtin_amdgcn_mfma_f32_16x16x32_bf16(af[mt][1], w1f[nt][1], a1, 0, 0, 0);
      f32x4 a2 = __builtin_amdgcn_mfma_f32_16x16x32_bf16(af[mt][0], w2f[nt][0],
                                                         (f32x4){0.f,0.f,0.f,0.f}, 0, 0, 0);
      a2 = __builtin_amdgcn_mfma_f32_16x16x32_bf16(af[mt][1], w2f[nt][1], a2, 0, 0, 0);
      const int j = nt * 16 + l;
      const float bb1 = b1[j], bb2 = b2[j];
      bf16x4 g4;
      #pragma unroll
      for (int r = 0; r < 4; ++r) {
        const int t = tb + mt * 16 + quad * 4 + r;
        const float v = (float)Vs[t * 64 + (((j >> 3) ^ (t & 7)) * 8) + (j & 7)];
        const float g = (v + a1[r] + bb1) * (1.0f / (1.0f + __expf(-(a2[r] + bb2))));
        g4[r] = f2bf(g);
      }
      *(bf16x4*)(GVt + (size_t)(bh64 + j) * T_ + t0 + tb + mt * 16 + quad * 4) = g4;
    }
  }
}

// ---------------- flash attention (causal), exp2-domain, static-shift softmax ----------------
// K-tile 32, 4-way split for occupancy: block = (pair pr, split s in 0..3, bh).
// Pair (qoA=pr, qoB=15-pr) has 4*(qoA+1)+4*(qoB+1) = 68 k32-units; each block does 17.
// Partials (O bf16, lsum fp32) from disjoint K-ranges combine by pure addition (static shift).
// Every [split][row] partial slot is written exactly once (zero-flush untouched tiles).
__global__ __launch_bounds__(256, 4)
void flash_kernel(const bf16* __restrict__ Q, const bf16* __restrict__ Kb,
                  const bf16* __restrict__ GVt,
                  bf16* __restrict__ PartO, float* __restrict__ PartL) {
  __shared__ bf16 Kd[2][2048];   // [kt=32][d=64], 16B chunks XOR-swizzled by (row&7)
  __shared__ bf16 Vd[2][2048];   // [d=64][kt=32], 16B chunks XOR-swizzled by (row&3)
  const int tid = threadIdx.x, w = tid >> 6, lane = tid & 63;
  const int l = lane & 15, quad = lane >> 4;
  const int idx = blockIdx.x;
  const int bh = idx & 31;              // same bh -> same XCD: K/V L2 locality
  const int s = (idx >> 5) & 3;
  const int pr = idx >> 7;              // 0..7
  const int qoA = pr, qoB = 15 - pr;
  const int nB = 4 * (qoB + 1);         // tile B's k32-unit count (36..64)
  const int u0 = 17 * s, u1 = u0 + 17;
  const int b = bh >> 4, h = bh & 15;
  const int bT = b * T_, hc = h * 64, bh64 = bh * 64;
  const int swz = l & 7;
  const size_t srowbase = (size_t)(s * 32 + bh) * 2048;

  f32x4 o[2][4];          // O^T accumulator: [mb][db], lane: q=l, d=db*16+quad*4+r
  float lsum[2];
  bf16x8 qa[2][2];

  auto resetacc = [&]() {
    #pragma unroll
    for (int mb = 0; mb < 2; ++mb) {
      #pragma unroll
      for (int db = 0; db < 4; ++db) o[mb][db] = (f32x4){0.f, 0.f, 0.f, 0.f};
      lsum[mb] = 0.f;
    }
  };
  auto loadqa = [&](int q0) {
    const int rb0 = q0 + w * 32;
    #pragma unroll
    for (int mb = 0; mb < 2; ++mb)
      #pragma unroll
      for (int kc = 0; kc < 2; ++kc)
        qa[mb][kc] = *(const bf16x8*)(Q + (size_t)(bT + rb0 + mb * 16 + l) * C_ + hc + kc * 32 + quad * 8);
  };
  auto u2kt = [&](int u, int& q0, int& kt) {
    if (u < nB) { q0 = qoB * 128; kt = u * 32; }
    else        { q0 = qoA * 128; kt = (u - nB) * 32; }
  };
  // async staging: each thread one 16B K-chunk + one 16B V-chunk; LDS dest is linear in tid
  // (wave-uniform base + lane*16); global src picks the chunk the XOR swizzle maps there.
  auto stage = [&](int kt, int bufn) {
    const int rowk = tid >> 3, ck = (tid & 7) ^ (rowk & 7);
    __builtin_amdgcn_global_load_lds(GLB(Kb + (size_t)(bT + kt + rowk) * C_ + hc + ck * 8),
                                     LDSP((char*)&Kd[bufn][0] + tid * 16), 16, 0, 0);
    const int rowv = tid >> 2, cv = (tid & 3) ^ (rowv & 3);
    __builtin_amdgcn_global_load_lds(GLB(GVt + (size_t)(bh64 + rowv) * T_ + kt + cv * 8),
                                     LDSP((char*)&Vd[bufn][0] + tid * 16), 16, 0, 0);
  };
  auto flush = [&](int q0) {           // write partials (bf16 O, fp32 lsum) for 32 rows
    const int rb0f = q0 + w * 32;
    #pragma unroll
    for (int mb = 0; mb < 2; ++mb) {
      float ls = lsum[mb];
      ls += __shfl_xor(ls, 16, 64);
      ls += __shfl_xor(ls, 32, 64);
      const int t = rb0f + mb * 16 + l;
      const size_t ro = (srowbase + t) * 64;
      #pragma unroll
      for (int db = 0; db < 4; ++db) {
        bf16x4 ov;
        #pragma unroll
        for (int r = 0; r < 4; ++r) ov[r] = f2bf(o[mb][db][r]);
        *(bf16x4*)(PartO + ro + db * 16 + quad * 4) = ov;
      }
      if (quad == 0) PartL[srowbase + t] = ls;
    }
  };

  int q0cur, kt0;
  u2kt(u0, q0cur, kt0);
  resetacc();
  loadqa(q0cur);
  stage(kt0, 0);
  __syncthreads();

  int buf = 0;
  for (int u = u0; u < u1; ++u, buf ^= 1) {
    if (u + 1 < u1) {                   // async prefetch, drained by end barrier
      int q0n, ktn;
      u2kt(u + 1, q0n, ktn);
      stage(ktn, buf ^ 1);
    }
    int q0u, ktu;
    u2kt(u, q0u, ktu);
    if (q0u != q0cur) {                 // pair boundary: flush tile B, switch to tile A
      flush(q0cur);
      resetacc();
      q0cur = q0u;
      loadqa(q0cur);
    }
    const int rb0 = q0cur + w * 32;

    if (ktu <= rb0 + 31) {  // wave-uniform: skip fully-masked units
      const bf16* Kc = &Kd[buf][0];
      const bf16* Vc = &Vd[buf][0];

      bf16x8 kf[2][2];      // K A-frags, 2 x 16-key tiles
      #pragma unroll
      for (int c = 0; c < 2; ++c)
        #pragma unroll
        for (int kc = 0; kc < 2; ++kc)
          kf[c][kc] = *(const bf16x8*)(Kc + (c * 16 + l) * 64 + (((4 * kc + quad) ^ swz) * 8));

      bf16x8 vfr[4];        // V^T A-frags: two b64 reads each
      #pragma unroll
      for (int db = 0; db < 4; ++db) {
        const int row = db * 16 + l;
        const int rs = l & 3;
        const int c0 = quad >> 1;
        const int sub = (quad & 1) * 4;
        union { bf16x8 v8; struct { bf16x4 lo, hi; } p; } uv;
        uv.p.lo = *(const bf16x4*)(Vc + row * 32 + ((c0 ^ rs) * 8) + sub);
        uv.p.hi = *(const bf16x4*)(Vc + row * 32 + (((c0 + 2) ^ rs) * 8) + sub);
        vfr[db] = uv.v8;
      }

      #pragma unroll
      for (int mb = 0; mb < 2; ++mb) {
        const int rowb = rb0 + mb * 16;
        if (ktu <= rowb + 15) {
          const int qrow = rowb + l;
          f32x4 sv[2];
          #pragma unroll
          for (int c = 0; c < 2; ++c) {
            sv[c] = __builtin_amdgcn_mfma_f32_16x16x32_bf16(kf[c][0], qa[mb][0],
                                                            (f32x4){0.f,0.f,0.f,0.f}, 0, 0, 0);
            sv[c] = __builtin_amdgcn_mfma_f32_16x16x32_bf16(kf[c][1], qa[mb][1], sv[c], 0, 0, 0);
          }
          #pragma unroll
          for (int c = 0; c < 2; ++c)
            if (ktu + c * 16 + 15 > rowb) {  // diagonal: mask key > q
              const int kb = ktu + c * 16 + quad * 4;
              #pragma unroll
              for (int r = 0; r < 4; ++r)
                if (kb + r > qrow) sv[c][r] = -1e30f;
            }
          float p[2][4];
          float ps = 0.f;
          #pragma unroll
          for (int c = 0; c < 2; ++c)
            #pragma unroll
            for (int r = 0; r < 4; ++r) { p[c][r] = exp2f(sv[c][r]); ps += p[c][r]; }
          lsum[mb] += ps;

          union { unsigned u[4]; bf16x8 v8; } pf;   // slot j: key (j>=4?16:0)+quad*4+(j&3)
          pf.u[0] = pk2bf(p[0][0], p[0][1]);
          pf.u[1] = pk2bf(p[0][2], p[0][3]);
          pf.u[2] = pk2bf(p[1][0], p[1][1]);
          pf.u[3] = pk2bf(p[1][2], p[1][3]);
          #pragma unroll
          for (int db = 0; db < 4; ++db)
            o[mb][db] = __builtin_amdgcn_mfma_f32_16x16x32_bf16(vfr[db], pf.v8, o[mb][db], 0, 0, 0);
        }
      }
    }
    __syncthreads();
  }

  flush(q0cur);
  resetacc();
  if (q0cur == qoB * 128)      flush(qoA * 128);  // never reached tile A: zero partials
  else if (u0 >= nB)           flush(qoB * 128);  // never touched tile B: zero partials
}

// ---------------- combine partials: Y = sum(O_s)/sum(l_s), cast bf16 ----------------
__global__ __launch_bounds__(256)
void combine_kernel(const bf16* __restrict__ PartO, const float* __restrict__ PartL,
                    bf16* __restrict__ Y) {
  const int e = blockIdx.x * 256 + threadIdx.x;   // 32*2048*16 threads (4 d each)
  const int dg = e & 15, row = e >> 4;            // row = bh*2048 + t
  const int bh = row >> 11, t = row & 2047;
  float ls = 0.f;
  float acc[4] = {0.f, 0.f, 0.f, 0.f};
  #pragma unroll
  for (int s = 0; s < 4; ++s) {
    ls += PartL[s * 65536 + row];
    const bf16x4 ov = *(const bf16x4*)(PartO + ((size_t)(s * 65536 + row)) * 64 + dg * 4);
    #pragma unroll
    for (int r = 0; r < 4; ++r) acc[r] += (float)ov[r];
  }
  const float inv = 1.0f / ls;
  const int b = bh >> 4, h = bh & 15;
  bf16x4 y;
  #pragma unroll
  for (int r = 0; r < 4; ++r) y[r] = f2bf(acc[r] * inv);
  *(bf16x4*)(Y + (size_t)(b * T_ + t) * C_ + h * 64 + dg * 4) = y;
}

// ---------------- launch ----------------
extern "C" void kernel_launch(void* const* d_in, const int* in_sizes, int n_in,
                              void* d_out, int out_size, void* d_ws, size_t ws_size,
                              hipStream_t stream) {
  const float* x      = (const float*)d_in[0];
  const float* W_attn = (const float*)d_in[1];
  const float* b_attn = (const float*)d_in[2];
  const float* W_l1   = (const float*)d_in[3];
  const float* b_l1   = (const float*)d_in[4];
  const float* W_l2   = (const float*)d_in[5];
  const float* b_l2   = (const float*)d_in[6];
  const float* W_proj = (const float*)d_in[7];
  const float* b_proj = (const float*)d_in[8];
  float* out = (float*)d_out;

  char* ws = (char*)d_ws;
  bf16* Xbf = (bf16*)(ws);                          //  8 MB  [M][C]
  bf16* WaT = (bf16*)(ws + ((size_t)8  << 20));     //  6 MB  [3C][C]
  bf16* WpT = (bf16*)(ws + ((size_t)14 << 20));     //  2 MB  [C][C]
  bf16* Qbf = (bf16*)(ws + ((size_t)16 << 20));     //  8 MB
  bf16* Kbf = (bf16*)(ws + ((size_t)24 << 20));     //  8 MB
  bf16* Vbf = (bf16*)(ws + ((size_t)32 << 20));     //  8 MB
  bf16* GVt = (bf16*)(ws + ((size_t)40 << 20));     //  8 MB  [b][h][d][t]
  bf16* Ybf = (bf16*)(ws + ((size_t)48 << 20));     //  8 MB
  bf16* PartO = (bf16*)(ws + ((size_t)56 << 20));   // 32 MB  [4][32*2048][64] bf16
  float* PartL = (float*)(ws + ((size_t)88 << 20)); //  1 MB  [4][32*2048] fp32
  bf16* W1T = (bf16*)(ws + ((size_t)89 << 20));     //  8 KB  [j][d]
  bf16* W2T = (bf16*)(ws + ((size_t)89 << 20) + 8192);

  cast_x_kernel<<<(M_ * C_ / 4 + 255) / 256, 256, 0, stream>>>(x, Xbf, M_ * C_ / 4);
  transpose_cast<<<dim3(N3_ / 32, C_ / 32), dim3(32, 8), 0, stream>>>(W_attn, WaT, C_, N3_);
  transpose_cast<<<dim3(C_ / 32, C_ / 32), dim3(32, 8), 0, stream>>>(W_proj, WpT, C_, C_);
  cast_wl_kernel<<<32, 256, 0, stream>>>(W_l1, W_l2, W1T, W2T);

  gemm128<0><<<dim3(N3_ / 128, M_ / 128), 256, 0, stream>>>(
      Xbf, WaT, b_attn, Qbf, Kbf, Vbf, nullptr, C_);

  gate_kernel<<<dim3(T_ / 128, B_ * H_), 256, 0, stream>>>(Vbf, W1T, b_l1, W2T, b_l2, GVt);

  flash_kernel<<<1024, 256, 0, stream>>>(Qbf, Kbf, GVt, PartO, PartL);

  combine_kernel<<<32 * 2048 * 16 / 256, 256, 0, stream>>>(PartO, PartL, Ybf);

  gemm128<1><<<dim3(C_ / 128, M_ / 128), 256, 0, stream>>>(
      Ybf, WpT, b_proj, nullptr, nullptr, nullptr, out, C_);

  (void)in_sizes; (void)n_in; (void)out_size; (void)ws_size;
}

// Round 7
// 221.326 us; speedup vs baseline: 1.0279x; 1.0279x over previous
//
#include <hip/hip_runtime.h>

#define B_  2
#define T_  2048
#define C_  1024
#define H_  16
#define HS_ 64
#define M_  4096   // B_*T_
#define N3_ 3072

typedef __bf16 bf16;
typedef bf16  bf16x4 __attribute__((ext_vector_type(4)));
typedef bf16  bf16x8 __attribute__((ext_vector_type(8)));
typedef float f32x4  __attribute__((ext_vector_type(4)));

__device__ __forceinline__ bf16 f2bf(float x) {
  union { float f; unsigned u; } v; v.f = x;
  unsigned r = (v.u + 0x7FFFu + ((v.u >> 16) & 1u)) >> 16;
  union { unsigned short s; bf16 b; } o; o.s = (unsigned short)r;
  return o.b;
}

// pack two fp32 -> two bf16 (round via +0x8000), lane-local, ~3 VALU ops
__device__ __forceinline__ unsigned pk2bf(float lo, float hi) {
  union { float f; unsigned u; } a, b;
  a.f = lo; b.f = hi;
  return ((a.u + 0x8000u) >> 16) | ((b.u + 0x8000u) & 0xFFFF0000u);
}

#define GLB(p) ((const __attribute__((address_space(1))) void*)(p))
#define LDSP(p) ((__attribute__((address_space(3))) void*)(p))

// ---------------- cast x -> bf16 ----------------
__global__ __launch_bounds__(256) void cast_x_kernel(const float* __restrict__ in,
                                                     bf16* __restrict__ out, int n4) {
  int i = blockIdx.x * 256 + threadIdx.x;
  if (i >= n4) return;
  float4 v = ((const float4*)in)[i];
  bf16 o[4] = {f2bf(v.x), f2bf(v.y), f2bf(v.z), f2bf(v.w)};
  *(uint2*)(out + (size_t)i * 4) = *(uint2*)o;
}

// ---------------- transpose + cast: in fp32 [R][Cc] -> out bf16 [Cc][R] ----------------
__global__ __launch_bounds__(256) void transpose_cast(const float* __restrict__ in,
                                                      bf16* __restrict__ out, int R, int Cc) {
  __shared__ float tile[32][33];
  int c0 = blockIdx.x * 32, r0 = blockIdx.y * 32;
  int tx = threadIdx.x, ty = threadIdx.y;
  #pragma unroll
  for (int i = ty; i < 32; i += 8)
    tile[i][tx] = in[(size_t)(r0 + i) * Cc + c0 + tx];
  __syncthreads();
  #pragma unroll
  for (int i = ty; i < 32; i += 8)
    out[(size_t)(c0 + i) * R + r0 + tx] = f2bf(tile[tx][i]);
}

// ---------------- transpose+cast W_l1/W_l2 (64x64 fp32) -> bf16 [j][d] ----------------
__global__ __launch_bounds__(256) void cast_wl_kernel(const float* __restrict__ W1,
                                                      const float* __restrict__ W2,
                                                      bf16* __restrict__ W1T,
                                                      bf16* __restrict__ W2T) {
  const int tid = blockIdx.x * 256 + threadIdx.x;   // 8192 total
  const int m = tid >> 12, e = tid & 4095;
  const int j = e >> 6, d = e & 63;
  const float* src = m ? W2 : W1;
  bf16* dst = m ? W2T : W1T;
  dst[e] = f2bf(src[d * 64 + j]);
}

// ------------- MTxN128 tile bf16 MFMA GEMM: C = A[M,K] * Bt[N,K]^T + bias -------------
// MODE 0: split epilogue -> Qo (x 0.125*log2e, exp2-domain flash), Ko, Vo (all bf16)
// MODE 1: fp32 out Fo [M][N].  MT in {64,128}; wave covers (MT/2) x 64.
template<int MODE, int MT>
__global__ __launch_bounds__(256)
void gemm128(const bf16* __restrict__ A, const bf16* __restrict__ Bt,
             const float* __restrict__ bias,
             bf16* __restrict__ Qo, bf16* __restrict__ Ko, bf16* __restrict__ Vo,
             float* __restrict__ Fo, int K) {
  constexpr int RB = MT / 32;            // 16-row tiles per wave
  __shared__ bf16 As[MT * 32];
  __shared__ bf16 Bs[128 * 32];
  const int tid = threadIdx.x;
  const int lane = tid & 63, w = tid >> 6;
  const int l = lane & 15, quad = lane >> 4;
  const int m0 = blockIdx.y * MT, n0 = blockIdx.x * 128;
  const int wm = (w >> 1) * (MT / 2), wn = (w & 1) * 64;

  f32x4 acc[RB][4];
  #pragma unroll
  for (int i = 0; i < RB; ++i)
    #pragma unroll
    for (int j = 0; j < 4; ++j)
      acc[i][j] = (f32x4){0.f, 0.f, 0.f, 0.f};

  for (int k0 = 0; k0 < K; k0 += 32) {
    #pragma unroll
    for (int ch = 0; ch < MT / 64; ++ch) {
      const int off = tid * 16 + ch * 4096;
      const int row = off >> 6;          // tile row (64B = 32 bf16 per row)
      const int ce  = (off & 63) >> 1;
      const bf16* ga = A + (size_t)(m0 + row) * K + (k0 + ce);
      __builtin_amdgcn_global_load_lds(GLB(ga), LDSP((char*)As + off), 16, 0, 0);
    }
    #pragma unroll
    for (int ch = 0; ch < 2; ++ch) {
      const int off = tid * 16 + ch * 4096;
      const int row = off >> 6;
      const int ce  = (off & 63) >> 1;
      const bf16* gb = Bt + (size_t)(n0 + row) * K + (k0 + ce);
      __builtin_amdgcn_global_load_lds(GLB(gb), LDSP((char*)Bs + off), 16, 0, 0);
    }
    __syncthreads();  // drains vmcnt before barrier (m97 structure)

    bf16x8 af[RB], bfr[4];
    #pragma unroll
    for (int rb = 0; rb < RB; ++rb)
      af[rb] = *(const bf16x8*)(As + (wm + rb * 16 + l) * 32 + quad * 8);
    #pragma unroll
    for (int cb = 0; cb < 4; ++cb)
      bfr[cb] = *(const bf16x8*)(Bs + (wn + cb * 16 + l) * 32 + quad * 8);
    #pragma unroll
    for (int rb = 0; rb < RB; ++rb)
      #pragma unroll
      for (int cb = 0; cb < 4; ++cb)
        acc[rb][cb] = __builtin_amdgcn_mfma_f32_16x16x32_bf16(af[rb], bfr[cb], acc[rb][cb], 0, 0, 0);
    __syncthreads();
  }

  #pragma unroll
  for (int rb = 0; rb < RB; ++rb) {
    #pragma unroll
    for (int cb = 0; cb < 4; ++cb) {
      #pragma unroll
      for (int r = 0; r < 4; ++r) {
        const int row = m0 + wm + rb * 16 + quad * 4 + r;
        const int col = n0 + wn + cb * 16 + l;
        float v = acc[rb][cb][r] + bias[col];
        if constexpr (MODE == 0) {
          const int seg = col >> 10, cc = col & 1023;
          const size_t idx = (size_t)row * C_ + cc;
          // Q scale = (1/sqrt(64)) * log2(e): flash softmax runs in exp2 domain
          if (seg == 0)      Qo[idx] = f2bf(v * 0.1803368801f);
          else if (seg == 1) Ko[idx] = f2bf(v);
          else               Vo[idx] = f2bf(v);
        } else {
          Fo[(size_t)row * C_ + col] = v;
        }
      }
    }
  }
}

// ---------------- v-gating via MFMA: gv = (v + v@W1 + b1) * sigmoid(v@W2 + b2) ----------------
// Writes GVt [b][h][j][t'] with INTERLEAVED key order within each 32-t block:
// position of key t (tm = t&31): pos = ((tm>>2)&3)*8 + (tm>>4)*4 + (tm&3).
// => one 16B chunk q holds keys {q*4..q*4+3} u {16+q*4..16+q*4+3} = one PV A-frag slice.
__global__ __launch_bounds__(256)
void gate_kernel(const bf16* __restrict__ V, const bf16* __restrict__ W1T,
                 const float* __restrict__ b1, const bf16* __restrict__ W2T,
                 const float* __restrict__ b2, bf16* __restrict__ GVt) {
  __shared__ bf16 Vs[128 * 64];
  __shared__ bf16 W1s[64 * 64];
  __shared__ bf16 W2s[64 * 64];
  const int tid = threadIdx.x, w = tid >> 6, lane = tid & 63;
  const int l = lane & 15, quad = lane >> 4;
  const int bh = blockIdx.y;
  const int t0 = blockIdx.x * 128;
  const int b = bh >> 4, h = bh & 15;
  const int bT = b * T_, hc = h * 64, bh64 = bh * 64;

  #pragma unroll
  for (int i = 0; i < 4; ++i) {
    const int p = tid + i * 256;
    const int row = p >> 3, cc = (p & 7) ^ (row & 7);
    const bf16* gv = V + (size_t)(bT + t0 + row) * C_ + hc + cc * 8;
    __builtin_amdgcn_global_load_lds(GLB(gv), LDSP((char*)Vs + p * 16), 16, 0, 0);
  }
  #pragma unroll
  for (int i = 0; i < 2; ++i) {
    const int p = tid + i * 256;
    const int row = p >> 3, cc = (p & 7) ^ (row & 7);
    __builtin_amdgcn_global_load_lds(GLB(W1T + row * 64 + cc * 8), LDSP((char*)W1s + p * 16), 16, 0, 0);
    __builtin_amdgcn_global_load_lds(GLB(W2T + row * 64 + cc * 8), LDSP((char*)W2s + p * 16), 16, 0, 0);
  }
  __syncthreads();

  const int tb = w * 32;
  bf16x8 af[2][2];
  #pragma unroll
  for (int mt = 0; mt < 2; ++mt) {
    const int row = tb + mt * 16 + l;
    #pragma unroll
    for (int kc = 0; kc < 2; ++kc)
      af[mt][kc] = *(const bf16x8*)(Vs + row * 64 + (((kc * 4 + quad) ^ (row & 7)) * 8));
  }
  bf16x8 w1f[4][2], w2f[4][2];
  #pragma unroll
  for (int nt = 0; nt < 4; ++nt) {
    const int row = nt * 16 + l;
    #pragma unroll
    for (int kc = 0; kc < 2; ++kc) {
      const int off = row * 64 + (((kc * 4 + quad) ^ (row & 7)) * 8);
      w1f[nt][kc] = *(const bf16x8*)(W1s + off);
      w2f[nt][kc] = *(const bf16x8*)(W2s + off);
    }
  }

  #pragma unroll
  for (int mt = 0; mt < 2; ++mt) {
    #pragma unroll
    for (int nt = 0; nt < 4; ++nt) {
      f32x4 a1 = __builtin_amdgcn_mfma_f32_16x16x32_bf16(af[mt][0], w1f[nt][0],
                                                         (f32x4){0.f,0.f,0.f,0.f}, 0, 0, 0);
      a1 = __builtin_amdgcn_mfma_f32_16x16x32_bf16(af[mt][1], w1f[nt][1], a1, 0, 0, 0);
      f32x4 a2 = __builtin_amdgcn_mfma_f32_16x16x32_bf16(af[mt][0], w2f[nt][0],
                                                         (f32x4){0.f,0.f,0.f,0.f}, 0, 0, 0);
      a2 = __builtin_amdgcn_mfma_f32_16x16x32_bf16(af[mt][1], w2f[nt][1], a2, 0, 0, 0);
      const int j = nt * 16 + l;
      const float bb1 = b1[j], bb2 = b2[j];
      bf16x4 g4;
      #pragma unroll
      for (int r = 0; r < 4; ++r) {
        const int t = tb + mt * 16 + quad * 4 + r;
        const float v = (float)Vs[t * 64 + (((j >> 3) ^ (t & 7)) * 8) + (j & 7)];
        const float g = (v + a1[r] + bb1) * (1.0f / (1.0f + __expf(-(a2[r] + bb2))));
        g4[r] = f2bf(g);
      }
      // interleaved position: 32-block = w, chunk = quad, half = mt
      *(bf16x4*)(GVt + (size_t)(bh64 + j) * T_ + t0 + w * 32 + quad * 8 + mt * 4) = g4;
    }
  }
}

// ---------------- flash attention (causal), exp2-domain, static-shift softmax ----------------
// K-tile 32, 4-way split: block = (pair pr, split s in 0..3, bh); each block = 17 k32-units.
// GVt is key-interleaved so a PV A-frag is ONE b128 LDS read (conflict-free via (l>>1)&3 swizzle).
__global__ __launch_bounds__(256, 3)
void flash_kernel(const bf16* __restrict__ Q, const bf16* __restrict__ Kb,
                  const bf16* __restrict__ GVt,
                  bf16* __restrict__ PartO, float* __restrict__ PartL) {
  __shared__ bf16 Kd[2][2048];   // [kt=32][d=64], 16B chunks XOR-swizzled by (row&7)
  __shared__ bf16 Vd[2][2048];   // [d=64][32 keys interleaved], chunks swizzled by (row>>1)&3
  const int tid = threadIdx.x, w = tid >> 6, lane = tid & 63;
  const int l = lane & 15, quad = lane >> 4;
  const int idx = blockIdx.x;
  const int bh = idx & 31;              // same bh -> same XCD: K/V L2 locality
  const int s = (idx >> 5) & 3;
  const int pr = idx >> 7;              // 0..7
  const int qoA = pr, qoB = 15 - pr;
  const int nB = 4 * (qoB + 1);         // tile B's k32-unit count (36..64)
  const int u0 = 17 * s, u1 = u0 + 17;
  const int b = bh >> 4, h = bh & 15;
  const int bT = b * T_, hc = h * 64, bh64 = bh * 64;
  const int swz = l & 7;
  const int swv = (l >> 1) & 3;
  const size_t srowbase = (size_t)(s * 32 + bh) * 2048;

  f32x4 o[2][4];          // O^T accumulator: [mb][db], lane: q=l, d=db*16+quad*4+r
  float lsum[2];
  bf16x8 qa[2][2];

  auto resetacc = [&]() {
    #pragma unroll
    for (int mb = 0; mb < 2; ++mb) {
      #pragma unroll
      for (int db = 0; db < 4; ++db) o[mb][db] = (f32x4){0.f, 0.f, 0.f, 0.f};
      lsum[mb] = 0.f;
    }
  };
  auto loadqa = [&](int q0) {
    const int rb0 = q0 + w * 32;
    #pragma unroll
    for (int mb = 0; mb < 2; ++mb)
      #pragma unroll
      for (int kc = 0; kc < 2; ++kc)
        qa[mb][kc] = *(const bf16x8*)(Q + (size_t)(bT + rb0 + mb * 16 + l) * C_ + hc + kc * 32 + quad * 8);
  };
  auto u2kt = [&](int u, int& q0, int& kt) {
    if (u < nB) { q0 = qoB * 128; kt = u * 32; }
    else        { q0 = qoA * 128; kt = (u - nB) * 32; }
  };
  auto stage = [&](int kt, int bufn) {
    const int rowk = tid >> 3, ck = (tid & 7) ^ (rowk & 7);
    __builtin_amdgcn_global_load_lds(GLB(Kb + (size_t)(bT + kt + rowk) * C_ + hc + ck * 8),
                                     LDSP((char*)&Kd[bufn][0] + tid * 16), 16, 0, 0);
    const int rowv = tid >> 2, cv = (tid & 3) ^ ((rowv >> 1) & 3);
    __builtin_amdgcn_global_load_lds(GLB(GVt + (size_t)(bh64 + rowv) * T_ + kt + cv * 8),
                                     LDSP((char*)&Vd[bufn][0] + tid * 16), 16, 0, 0);
  };
  auto flush = [&](int q0) {           // write partials (bf16 O, fp32 lsum) for 32 rows
    const int rb0f = q0 + w * 32;
    #pragma unroll
    for (int mb = 0; mb < 2; ++mb) {
      float ls = lsum[mb];
      ls += __shfl_xor(ls, 16, 64);
      ls += __shfl_xor(ls, 32, 64);
      const int t = rb0f + mb * 16 + l;
      const size_t ro = (srowbase + t) * 64;
      #pragma unroll
      for (int db = 0; db < 4; ++db) {
        bf16x4 ov;
        #pragma unroll
        for (int r = 0; r < 4; ++r) ov[r] = f2bf(o[mb][db][r]);
        *(bf16x4*)(PartO + ro + db * 16 + quad * 4) = ov;
      }
      if (quad == 0) PartL[srowbase + t] = ls;
    }
  };

  int q0cur, kt0;
  u2kt(u0, q0cur, kt0);
  resetacc();
  loadqa(q0cur);
  stage(kt0, 0);
  __syncthreads();

  int buf = 0;
  for (int u = u0; u < u1; ++u, buf ^= 1) {
    if (u + 1 < u1) {                   // async prefetch, drained by end barrier
      int q0n, ktn;
      u2kt(u + 1, q0n, ktn);
      stage(ktn, buf ^ 1);
    }
    int q0u, ktu;
    u2kt(u, q0u, ktu);
    if (q0u != q0cur) {                 // pair boundary: flush tile B, switch to tile A
      flush(q0cur);
      resetacc();
      q0cur = q0u;
      loadqa(q0cur);
    }
    const int rb0 = q0cur + w * 32;

    if (ktu <= rb0 + 31) {  // wave-uniform: skip fully-masked units
      const bf16* Kc = &Kd[buf][0];
      const bf16* Vc = &Vd[buf][0];

      bf16x8 kf[2][2];      // K A-frags, 2 x 16-key tiles
      #pragma unroll
      for (int c = 0; c < 2; ++c)
        #pragma unroll
        for (int kc = 0; kc < 2; ++kc)
          kf[c][kc] = *(const bf16x8*)(Kc + (c * 16 + l) * 64 + (((4 * kc + quad) ^ swz) * 8));

      bf16x8 vfr[4];        // V^T A-frags: ONE b128 each (interleaved chunk)
      #pragma unroll
      for (int db = 0; db < 4; ++db)
        vfr[db] = *(const bf16x8*)(Vc + (db * 16 + l) * 32 + ((quad ^ swv) * 8));

      #pragma unroll
      for (int mb = 0; mb < 2; ++mb) {
        const int rowb = rb0 + mb * 16;
        if (ktu <= rowb + 15) {
          const int qrow = rowb + l;
          f32x4 sv[2];
          #pragma unroll
          for (int c = 0; c < 2; ++c) {
            sv[c] = __builtin_amdgcn_mfma_f32_16x16x32_bf16(kf[c][0], qa[mb][0],
                                                            (f32x4){0.f,0.f,0.f,0.f}, 0, 0, 0);
            sv[c] = __builtin_amdgcn_mfma_f32_16x16x32_bf16(kf[c][1], qa[mb][1], sv[c], 0, 0, 0);
          }
          #pragma unroll
          for (int c = 0; c < 2; ++c)
            if (ktu + c * 16 + 15 > rowb) {  // diagonal: mask key > q
              const int kb = ktu + c * 16 + quad * 4;
              #pragma unroll
              for (int r = 0; r < 4; ++r)
                if (kb + r > qrow) sv[c][r] = -1e30f;
            }
          float p[2][4];
          float ps = 0.f;
          #pragma unroll
          for (int c = 0; c < 2; ++c)
            #pragma unroll
            for (int r = 0; r < 4; ++r) { p[c][r] = exp2f(sv[c][r]); ps += p[c][r]; }
          lsum[mb] += ps;

          union { unsigned u[4]; bf16x8 v8; } pf;   // slot j: key (j>=4?16:0)+quad*4+(j&3)
          pf.u[0] = pk2bf(p[0][0], p[0][1]);
          pf.u[1] = pk2bf(p[0][2], p[0][3]);
          pf.u[2] = pk2bf(p[1][0], p[1][1]);
          pf.u[3] = pk2bf(p[1][2], p[1][3]);
          #pragma unroll
          for (int db = 0; db < 4; ++db)
            o[mb][db] = __builtin_amdgcn_mfma_f32_16x16x32_bf16(vfr[db], pf.v8, o[mb][db], 0, 0, 0);
        }
      }
    }
    __syncthreads();
  }

  flush(q0cur);
  resetacc();
  if (q0cur == qoB * 128)      flush(qoA * 128);  // never reached tile A: zero partials
  else if (u0 >= nB)           flush(qoB * 128);  // never touched tile B: zero partials
}

// ---------------- combine partials: Y = sum(O_s)/sum(l_s), cast bf16 ----------------
__global__ __launch_bounds__(256)
void combine_kernel(const bf16* __restrict__ PartO, const float* __restrict__ PartL,
                    bf16* __restrict__ Y) {
  const int e = blockIdx.x * 256 + threadIdx.x;   // 32*2048*16 threads (4 d each)
  const int dg = e & 15, row = e >> 4;            // row = bh*2048 + t
  const int bh = row >> 11, t = row & 2047;
  float ls = 0.f;
  float acc[4] = {0.f, 0.f, 0.f, 0.f};
  #pragma unroll
  for (int s = 0; s < 4; ++s) {
    ls += PartL[s * 65536 + row];
    const bf16x4 ov = *(const bf16x4*)(PartO + ((size_t)(s * 65536 + row)) * 64 + dg * 4);
    #pragma unroll
    for (int r = 0; r < 4; ++r) acc[r] += (float)ov[r];
  }
  const float inv = 1.0f / ls;
  const int b = bh >> 4, h = bh & 15;
  bf16x4 y;
  #pragma unroll
  for (int r = 0; r < 4; ++r) y[r] = f2bf(acc[r] * inv);
  *(bf16x4*)(Y + (size_t)(b * T_ + t) * C_ + h * 64 + dg * 4) = y;
}

// ---------------- launch ----------------
extern "C" void kernel_launch(void* const* d_in, const int* in_sizes, int n_in,
                              void* d_out, int out_size, void* d_ws, size_t ws_size,
                              hipStream_t stream) {
  const float* x      = (const float*)d_in[0];
  const float* W_attn = (const float*)d_in[1];
  const float* b_attn = (const float*)d_in[2];
  const float* W_l1   = (const float*)d_in[3];
  const float* b_l1   = (const float*)d_in[4];
  const float* W_l2   = (const float*)d_in[5];
  const float* b_l2   = (const float*)d_in[6];
  const float* W_proj = (const float*)d_in[7];
  const float* b_proj = (const float*)d_in[8];
  float* out = (float*)d_out;

  char* ws = (char*)d_ws;
  bf16* Xbf = (bf16*)(ws);                          //  8 MB  [M][C]
  bf16* WaT = (bf16*)(ws + ((size_t)8  << 20));     //  6 MB  [3C][C]
  bf16* WpT = (bf16*)(ws + ((size_t)14 << 20));     //  2 MB  [C][C]
  bf16* Qbf = (bf16*)(ws + ((size_t)16 << 20));     //  8 MB
  bf16* Kbf = (bf16*)(ws + ((size_t)24 << 20));     //  8 MB
  bf16* Vbf = (bf16*)(ws + ((size_t)32 << 20));     //  8 MB
  bf16* GVt = (bf16*)(ws + ((size_t)40 << 20));     //  8 MB  [b][h][j][t interleaved]
  bf16* Ybf = (bf16*)(ws + ((size_t)48 << 20));     //  8 MB
  bf16* PartO = (bf16*)(ws + ((size_t)56 << 20));   // 32 MB  [4][32*2048][64] bf16
  float* PartL = (float*)(ws + ((size_t)88 << 20)); //  1 MB  [4][32*2048] fp32
  bf16* W1T = (bf16*)(ws + ((size_t)89 << 20));     //  8 KB  [j][d]
  bf16* W2T = (bf16*)(ws + ((size_t)89 << 20) + 8192);

  cast_x_kernel<<<(M_ * C_ / 4 + 255) / 256, 256, 0, stream>>>(x, Xbf, M_ * C_ / 4);
  transpose_cast<<<dim3(N3_ / 32, C_ / 32), dim3(32, 8), 0, stream>>>(W_attn, WaT, C_, N3_);
  transpose_cast<<<dim3(C_ / 32, C_ / 32), dim3(32, 8), 0, stream>>>(W_proj, WpT, C_, C_);
  cast_wl_kernel<<<32, 256, 0, stream>>>(W_l1, W_l2, W1T, W2T);

  gemm128<0, 128><<<dim3(N3_ / 128, M_ / 128), 256, 0, stream>>>(
      Xbf, WaT, b_attn, Qbf, Kbf, Vbf, nullptr, C_);

  gate_kernel<<<dim3(T_ / 128, B_ * H_), 256, 0, stream>>>(Vbf, W1T, b_l1, W2T, b_l2, GVt);

  flash_kernel<<<1024, 256, 0, stream>>>(Qbf, Kbf, GVt, PartO, PartL);

  combine_kernel<<<32 * 2048 * 16 / 256, 256, 0, stream>>>(PartO, PartL, Ybf);

  gemm128<1, 64><<<dim3(C_ / 128, M_ / 64), 256, 0, stream>>>(
      Ybf, WpT, b_proj, nullptr, nullptr, nullptr, out, C_);

  (void)in_sizes; (void)n_in; (void)out_size; (void)ws_size;
}